// Round 3
// baseline (40.224 us; speedup 1.0000x reference)
//
#include <hip/hip_runtime.h>

#define NN 512   // points per event (N == M)
#define DD 9     // num classes
#define LL 32    // latent dim

// grid = 1024: block = (b, p, h). b = batch, p = pass (0: input rows vs preds,
// 1: pred rows vs inputs), h = row half. 256 threads: rg = t>>3 owns 8 rows,
// seg = t&7 scans m = seg+8j (64 iters). Exact first-index argmin restored by
// lexicographic (d, idx) combine across the 8 segments.
__global__ __launch_bounds__(256, 5)
void loss_kernel(const float* __restrict__ kine_input,
                 const float* __restrict__ class_input,
                 const float* __restrict__ kine_pred,
                 const float* __restrict__ class_pred,
                 const float* __restrict__ mu,
                 const float* __restrict__ log_var,
                 float* __restrict__ out)
{
    const int bid = (int)blockIdx.x;
    const int b = bid >> 2;
    const int p = (bid >> 1) & 1;
    const int h = bid & 1;
    const int t = (int)threadIdx.x;   // 0..255

    __shared__ float4 sy4[NN];        // full opposing point set
    __shared__ float  sy2[NN];        // its squared norms
    __shared__ float4 sx4[NN/2];      // our half's points
    __shared__ float  sx2[NN/2];
    __shared__ float  comb_d[8][257]; // per-segment partial min (padded)
    __shared__ int    comb_i[8][257];
    __shared__ float  red[4];
    __shared__ int    hist_in[DD], hist_pr[DD];

    const float* Xg = p ? kine_pred  : kine_input;
    const float* Yg = p ? kine_input : kine_pred;

    // ---- stage Y (full) and X (our half) with squared norms ----
    {
        float4 v0 = *reinterpret_cast<const float4*>(Yg + ((size_t)b*NN + t)*4);
        sy4[t] = v0; sy2[t] = v0.x*v0.x + v0.y*v0.y + v0.z*v0.z + v0.w*v0.w;
        float4 v1 = *reinterpret_cast<const float4*>(Yg + ((size_t)b*NN + 256 + t)*4);
        sy4[256+t] = v1; sy2[256+t] = v1.x*v1.x + v1.y*v1.y + v1.z*v1.z + v1.w*v1.w;
        float4 xv = *reinterpret_cast<const float4*>(Xg + ((size_t)b*NN + h*256 + t)*4);
        sx4[t] = xv; sx2[t] = xv.x*xv.x + xv.y*xv.y + xv.z*xv.z + xv.w*xv.w;
    }
    if (t < DD) { hist_in[t] = 0; hist_pr[t] = 0; }
    __syncthreads();

    // ---- histograms + KL: (p==0,h==0) block only; labels don't depend on argmins ----
    float kl = 0.f;
    if (p == 0 && h == 0) {
        #pragma unroll
        for (int rr = 0; rr < 2; ++rr) {
            const float* ci = class_input + ((size_t)b*NN + t + rr*256)*DD;
            float mx = ci[0]; int lab = 0;
            #pragma unroll
            for (int d2 = 1; d2 < DD; ++d2) { float v = ci[d2]; if (v > mx) { mx = v; lab = d2; } }
            atomicAdd(&hist_in[lab], 1);
            const float* cp = class_pred + ((size_t)b*NN + t + rr*256)*DD;
            mx = cp[0]; lab = 0;
            #pragma unroll
            for (int d2 = 1; d2 < DD; ++d2) { float v = cp[d2]; if (v > mx) { mx = v; lab = d2; } }  // argmax(exp)==argmax
            atomicAdd(&hist_pr[lab], 1);
        }
        if (t < LL) {
            float m_ = mu[(size_t)b*LL + t];
            float lv = log_var[(size_t)b*LL + t];
            kl = 1.f + lv - m_*m_ - expf(lv);
        }
    }
    if (t < 64) {
        #pragma unroll
        for (int off = 32; off > 0; off >>= 1) kl += __shfl_down(kl, off, 64);
    }

    // ---- main distance pass: 8 rows/thread, m-segmented x8 ----
    const int rg   = t >> 3;       // 0..31
    const int seg  = t & 7;        // 0..7
    const int lrow0 = rg * 8;

    float4 a[8]; float x2q[8]; float best[8]; int bidx[8];
    #pragma unroll
    for (int q = 0; q < 8; ++q) {
        float4 xv = sx4[lrow0 + q];
        a[q] = make_float4(-2.f*xv.x, -2.f*xv.y, -2.f*xv.z, -2.f*xv.w);
        x2q[q] = sx2[lrow0 + q];
        best[q] = 1e30f; bidx[q] = 0;
    }

    #pragma unroll 2
    for (int j = 0; j < 64; ++j) {
        const int m = seg + 8*j;
        float4 yv = sy4[m];   // 8 consecutive addrs/wave, 8-lane broadcast: conflict-free
        float  y2 = sy2[m];
        #pragma unroll
        for (int q = 0; q < 8; ++q) {
            float d = fmaf(a[q].x, yv.x, fmaf(a[q].y, yv.y,
                      fmaf(a[q].z, yv.z, fmaf(a[q].w, yv.w, x2q[q] + y2))));
            if (d < best[q]) { best[q] = d; bidx[q] = m; }   // strict <: first index in-segment
        }
    }

    #pragma unroll
    for (int q = 0; q < 8; ++q) {
        comb_d[seg][lrow0 + q] = best[q];
        comb_i[seg][lrow0 + q] = bidx[q];
    }
    __syncthreads();

    // ---- per-row finalize: thread t owns local row t ----
    float part;
    {
        float bd = comb_d[0][t]; int bi = comb_i[0][t];
        #pragma unroll
        for (int s2 = 1; s2 < 8; ++s2) {
            float d = comb_d[s2][t]; int i2 = comb_i[s2][t];
            if (d < bd || (d == bd && i2 < bi)) { bd = d; bi = i2; }  // global first-index
        }
        const int grow = h*256 + t;
        const float* own = (p ? class_pred  : class_input) + ((size_t)b*NN + grow)*DD;
        const float* oth = (p ? class_input : class_pred)  + ((size_t)b*NN + bi)*DD;
        float dot = 0.f;
        #pragma unroll
        for (int d2 = 0; d2 < DD; ++d2) dot += own[d2]*oth[d2];
        part = bd - dot;   // chamfer + (-1)*class dot (W=1)
    }

    // ---- block reduce (4 waves) ----
    #pragma unroll
    for (int off = 32; off > 0; off >>= 1) part += __shfl_down(part, off, 64);
    if ((t & 63) == 0) red[t >> 6] = part;
    __syncthreads();

    if (t == 0) {
        float sum = red[0] + red[1] + red[2] + red[3];
        float val = 0.99f * sum;
        if (p == 0 && h == 0) {
            float cnum = 0.f;
            #pragma unroll
            for (int c = 0; c < DD; ++c) {
                float diff = fabsf((float)(hist_pr[c] - hist_in[c]));
                float wgt = (c == 0) ? 2.0f : ((c == DD-1) ? 100.0f : 1.0f);
                cnum += wgt * diff;
            }
            val += 0.99f * 0.001f * cnum + 0.01f * (-0.5f * kl);
        }
        atomicAdd(out + b, val);
    }
}

extern "C" void kernel_launch(void* const* d_in, const int* in_sizes, int n_in,
                              void* d_out, int out_size, void* d_ws, size_t ws_size,
                              hipStream_t stream) {
    const float* kine_input  = (const float*)d_in[0];
    const float* class_input = (const float*)d_in[1];
    const float* kine_pred   = (const float*)d_in[2];
    const float* class_pred  = (const float*)d_in[3];
    const float* mu          = (const float*)d_in[4];
    const float* log_var     = (const float*)d_in[5];
    float* out = (float*)d_out;

    hipMemsetAsync(d_out, 0, (size_t)out_size * sizeof(float), stream);
    loss_kernel<<<1024, 256, 0, stream>>>(kine_input, class_input, kine_pred,
                                          class_pred, mu, log_var, out);
}